// Round 17
// baseline (386.749 us; speedup 1.0000x reference)
//
#include <hip/hip_runtime.h>
#include <hip/hip_bf16.h>
#include <math.h>

// B=4, N=4096 -> 16384 windows of NHT=16 tokens, MD=128
#define NHT 16
#define MD 128
#define FFD 256
#define NHEAD 4
#define DH 32
#define PED 32
#define ED 64
#define SCALE 0.17677669529663687f
#define SCB 136      // short stride, bf16 [16][128] tiles (272 B rows)
#define SCUF 264     // short stride, full FFN u tile [16][256]

typedef __attribute__((ext_vector_type(8))) short bf8;
typedef __attribute__((ext_vector_type(4))) float f32x4;
union U8 { bf8 v; unsigned short s[8]; uint u[4]; uint4 q; };

#define MFMA __builtin_amdgcn_mfma_f32_16x16x32_bf16

__device__ __forceinline__ unsigned short bf1(float a){
  __hip_bfloat16 h = __float2bfloat16(a);
  return *reinterpret_cast<unsigned short*>(&h);
}
__device__ __forceinline__ float bfh2f(unsigned short s){
  __hip_bfloat16 h = *reinterpret_cast<__hip_bfloat16*>(&s);
  return __bfloat162float(h);
}
// silu with fast hardware reciprocal (v_rcp_f32) instead of IEEE divide
__device__ __forceinline__ float silu_f(float x){
  return x * __builtin_amdgcn_rcpf(1.f + __expf(-x));
}

// VERIFIED (r8/r11/r12): butterfly LN on MFMA C-layout tile
__device__ __forceinline__ void lnC(float (&C)[8][4], const float* __restrict__ g,
                                    const float* __restrict__ b, int lm){
#pragma unroll
  for (int r = 0; r < 4; ++r){
    float s = 0.f, ss = 0.f;
#pragma unroll
    for (int nt = 0; nt < 8; ++nt){ s += C[nt][r]; ss = fmaf(C[nt][r], C[nt][r], ss); }
#pragma unroll
    for (int m = 1; m < 16; m <<= 1){ s += __shfl_xor(s, m); ss += __shfl_xor(ss, m); }
    float mean = s * (1.f/128.f);
    float var  = ss * (1.f/128.f) - mean*mean;
    float rs   = rsqrtf(var + 1e-5f);
#pragma unroll
    for (int nt = 0; nt < 8; ++nt)
      C[nt][r] = fmaf((C[nt][r] - mean) * rs, g[nt*16+lm], b[nt*16+lm]);
  }
}

// ---- weight pre-pack (verified r5-r12): fp32 [K][N] -> bf16 B-frag order; 256 KiB ----
__global__ __launch_bounds__(256)
void packw(const float* __restrict__ Wq, const float* __restrict__ Wk,
           const float* __restrict__ Wv, const float* __restrict__ Wo,
           const float* __restrict__ W1, const float* __restrict__ W2,
           uint4* __restrict__ ws){
  int id = blockIdx.x * 256 + threadIdx.x;   // 16384 total
  const float* W; int KT, N, u; uint4* dst;
  if      (id < 2048) { W = Wq;  KT = 4; N = 128; dst = ws;         u = id;         }
  else if (id < 4096) { W = Wk;  KT = 4; N = 128; dst = ws + 2048;  u = id - 2048;  }
  else if (id < 6144) { W = Wv;  KT = 4; N = 128; dst = ws + 4096;  u = id - 4096;  }
  else if (id < 8192) { W = Wo;  KT = 4; N = 128; dst = ws + 6144;  u = id - 6144;  }
  else if (id < 12288){ W = W1;  KT = 4; N = 256; dst = ws + 8192;  u = id - 8192;  }
  else                { W = W2;  KT = 8; N = 128; dst = ws + 12288; u = id - 12288; }
  int lane = u & 63, tile = u >> 6;
  int kt = tile % KT, nt = tile / KT;
  int kr  = kt*32 + ((lane >> 4) << 3);
  int col = nt*16 + (lane & 15);
  const float* p = W + (size_t)kr * N + col;
  U8 hi;
#pragma unroll
  for (int j = 0; j < 8; ++j) hi.s[j] = bf1(p[(size_t)j * N]);
  dst[u] = hi.q;
}

// W_in pack (verified r12) -> ws + 16384 units; launched only if ws_size allows.
__global__ __launch_bounds__(256)
void packwin(const float* __restrict__ Win, uint4* __restrict__ ws){
  int u = blockIdx.x * 256 + threadIdx.x;   // 1024 total
  int lane = u & 63, tile = u >> 6;
  int kt = tile % 2, nt = tile / 2;
  int kr  = kt*32 + ((lane >> 4) << 3);
  int col = nt*16 + (lane & 15);
  const float* p = Win + (size_t)kr * MD + col;
  U8 hi;
#pragma unroll
  for (int j = 0; j < 8; ++j) hi.s[j] = bf1(p[(size_t)j * MD]);
  ws[16384 + u] = hi.q;
}

// r12 single-wave structure; MFMA attention (r2 construction, dedicated buffers).
__global__ __launch_bounds__(64)
void nha_mfma(const float* __restrict__ x, const float* __restrict__ pos1,
              const float* __restrict__ pos2,
              const float* __restrict__ W_in,
              const float* __restrict__ g_in, const float* __restrict__ b_in,
              const float* __restrict__ W_pe, const float* __restrict__ W_bias,
              const float* __restrict__ bq, const float* __restrict__ bk,
              const float* __restrict__ bv, const float* __restrict__ bo,
              const float* __restrict__ g1, const float* __restrict__ b1,
              const float* __restrict__ g2, const float* __restrict__ b2,
              const uint4* __restrict__ wsp, int useWin, float* __restrict__ out)
{
  const uint4* pWq  = wsp;
  const uint4* pWk  = wsp + 2048;
  const uint4* pWv  = wsp + 4096;
  const uint4* pWo  = wsp + 6144;
  const uint4* pW1  = wsp + 8192;
  const uint4* pW2  = wsp + 12288;
  const uint4* pWin = wsp + 16384;

  // dedicated, non-aliased buffers
  __shared__ __align__(16) unsigned short Qb[NHT*SCB];   // q rows; later o rows
  __shared__ __align__(16) unsigned short Kb[NHT*SCB];   // k rows
  __shared__ __align__(16) unsigned short Vt[MD*NHT];    // V^T [d=128][ki=16]
  __shared__ __align__(16) unsigned short Pb[NHT*SCB];   // att rows (per-head 32-col slots)
  __shared__ __align__(16) unsigned short Tb[NHT*SCB];   // t bounce; later y bounce
  __shared__ __align__(16) unsigned short Ub[NHT*SCUF];  // FFN u, full width
  __shared__ __align__(16) float Bsm[NHEAD*NHT*NHT];

  const int tid = threadIdx.x;   // one wave per block/window
  const int wi  = blockIdx.x;
  const int lm  = tid & 15;
  const int lg  = tid >> 4;
  const f32x4 zero4 = {0.f,0.f,0.f,0.f};
  const bf8  zero8 = {0,0,0,0,0,0,0,0};

  // ========== Stage A: t = x @ W_in (hi-only) ==========
  bf8 xA[2];
  {
    const float* xp = x + (size_t)wi*1024 + lm*ED + lg*8;
#pragma unroll
    for (int kt = 0; kt < 2; ++kt){
      U8 h;
#pragma unroll
      for (int j = 0; j < 8; ++j) h.s[j] = bf1(xp[kt*32 + j]);
      xA[kt] = h.v;
    }
  }
  float tC[8][4];
#pragma unroll
  for (int nt = 0; nt < 8; ++nt){
    f32x4 acc = zero4;
#pragma unroll
    for (int kt = 0; kt < 2; ++kt){
      U8 w;
      if (useWin){
        w.q = pWin[(nt*2+kt)*64 + tid];
      } else {
        const float* wp = W_in + (size_t)(kt*32 + lg*8)*MD + nt*16 + lm;
#pragma unroll
        for (int j = 0; j < 8; ++j) w.s[j] = bf1(wp[(size_t)j*MD]);
      }
      acc = MFMA(xA[kt], w.v, acc, 0,0,0);
    }
#pragma unroll
    for (int r = 0; r < 4; ++r) tC[nt][r] = acc[r];
  }
  lnC(tC, g_in, b_in, lm);

  // ========== bounce t (bf16) -> A-frags ==========
#pragma unroll
  for (int nt = 0; nt < 8; ++nt)
#pragma unroll
    for (int r = 0; r < 4; ++r)
      Tb[(lg*4+r)*SCB + nt*16+lm] = bf1(tC[nt][r]);
  __syncthreads();
  bf8 tA[4];
#pragma unroll
  for (int kt = 0; kt < 4; ++kt)
    tA[kt] = *(const bf8*)(Tb + lm*SCB + kt*32 + lg*8);
  __syncthreads();

  // ========== Q,K (bf16 rows), V (transposed bf16) = t@W + b ==========
#pragma unroll
  for (int nt = 0; nt < 8; ++nt){
    float bb = bq[nt*16+lm];
    f32x4 acc = {bb,bb,bb,bb};
#pragma unroll
    for (int kt = 0; kt < 4; ++kt){
      U8 bh; bh.q = pWq[(nt*4+kt)*64 + tid];
      acc = MFMA(tA[kt], bh.v, acc, 0,0,0);
    }
#pragma unroll
    for (int r = 0; r < 4; ++r) Qb[(lg*4+r)*SCB + nt*16+lm] = bf1(acc[r]);
  }
#pragma unroll
  for (int nt = 0; nt < 8; ++nt){
    float bb = bk[nt*16+lm];
    f32x4 acc = {bb,bb,bb,bb};
#pragma unroll
    for (int kt = 0; kt < 4; ++kt){
      U8 bh; bh.q = pWk[(nt*4+kt)*64 + tid];
      acc = MFMA(tA[kt], bh.v, acc, 0,0,0);
    }
#pragma unroll
    for (int r = 0; r < 4; ++r) Kb[(lg*4+r)*SCB + nt*16+lm] = bf1(acc[r]);
  }
#pragma unroll
  for (int nt = 0; nt < 8; ++nt){
    float bb = bv[nt*16+lm];
    f32x4 acc = {bb,bb,bb,bb};
#pragma unroll
    for (int kt = 0; kt < 4; ++kt){
      U8 bh; bh.q = pWv[(nt*4+kt)*64 + tid];
      acc = MFMA(tA[kt], bh.v, acc, 0,0,0);
    }
    // V^T store: Vt[d][ki], d = col = nt*16+lm, ki = row = lg*4+r
#pragma unroll
    for (int r = 0; r < 4; ++r) Vt[(nt*16+lm)*NHT + lg*4+r] = bf1(acc[r]);
  }

  // ========== rel-pos bias -> Bsm (fp32, rcpf silu) ==========
  for (int p = tid; p < NHT*NHT; p += 64){
    float p1 = pos1[(size_t)wi*256 + p];
    float p2 = pos2[(size_t)wi*256 + p];
    float a0=0.f, a1=0.f, a2=0.f, a3=0.f;
#pragma unroll
    for (int i = 0; i < PED; ++i){
      float e = fmaf(p1, W_pe[i], p2 * W_pe[PED+i]);
      float sv = silu_f(e);
      a0 = fmaf(sv, W_bias[i*4+0], a0);
      a1 = fmaf(sv, W_bias[i*4+1], a1);
      a2 = fmaf(sv, W_bias[i*4+2], a2);
      a3 = fmaf(sv, W_bias[i*4+3], a3);
    }
    Bsm[0*256 + p] = a0; Bsm[1*256 + p] = a1; Bsm[2*256 + p] = a2; Bsm[3*256 + p] = a3;
  }
  __syncthreads();

  // ========== attention via MFMA (r2 construction, dedicated buffers) ==========
  // S_h = Q_h @ K_h^T : A-frag = Q row lm cols h*32+lg*8 ; B-frag = K row lm (K^T cols)
  bf8 qA[4], kB[4];
#pragma unroll
  for (int h = 0; h < 4; ++h){
    qA[h] = *(const bf8*)(Qb + lm*SCB + h*32 + lg*8);
    kB[h] = *(const bf8*)(Kb + lm*SCB + h*32 + lg*8);
  }
#pragma unroll
  for (int h = 0; h < 4; ++h){
    f32x4 s = MFMA(qA[h], kB[h], zero4, 0,0,0);
    // softmax over ki (= lm lanes), rows qi = lg*4+r — lnC's verified butterfly
#pragma unroll
    for (int r = 0; r < 4; ++r){
      float v = fmaf(s[r], SCALE, Bsm[h*256 + (lg*4+r)*16 + lm]);
      float mx = v;
#pragma unroll
      for (int m = 1; m < 16; m <<= 1) mx = fmaxf(mx, __shfl_xor(mx, m));
      float e = __expf(v - mx);
      float sm = e;
#pragma unroll
      for (int m = 1; m < 16; m <<= 1) sm += __shfl_xor(sm, m);
      Pb[(lg*4+r)*SCB + h*32 + lm] = bf1(e * __builtin_amdgcn_rcpf(sm));
    }
  }
  __syncthreads();

  // PV: O_h = P_h @ V_h  (K=32, upper 16 k zeroed via A)
#pragma unroll
  for (int h = 0; h < 4; ++h){
    bf8 aP = *(const bf8*)(Pb + lm*SCB + h*32 + lg*8);
    if (tid >= 32) aP = zero8;        // k = lg*8+j >= 16 -> zero contribution
#pragma unroll
    for (int n2 = 0; n2 < 2; ++n2){
      bf8 vB = *(const bf8*)(Vt + (h*32 + n2*16 + lm)*NHT + (lg & 1)*8);
      if (tid >= 32) vB = zero8;
      f32x4 o = MFMA(aP, vB, zero4, 0,0,0);
      // o rows over Qb (q fully consumed into qA regs)
#pragma unroll
      for (int r = 0; r < 4; ++r)
        Qb[(lg*4+r)*SCB + h*32 + n2*16 + lm] = bf1(o[r]);
    }
  }
  __syncthreads();

  // ========== att_out = o@Wo + bo, residual, LN1 ==========
  bf8 oA[4];
#pragma unroll
  for (int kt = 0; kt < 4; ++kt)
    oA[kt] = *(const bf8*)(Qb + lm*SCB + kt*32 + lg*8);
#pragma unroll
  for (int nt = 0; nt < 8; ++nt){
    float bb = bo[nt*16+lm];
    f32x4 acc = {bb,bb,bb,bb};
#pragma unroll
    for (int kt = 0; kt < 4; ++kt){
      U8 bh; bh.q = pWo[(nt*4+kt)*64 + tid];
      acc = MFMA(oA[kt], bh.v, acc, 0,0,0);
    }
#pragma unroll
    for (int r = 0; r < 4; ++r) tC[nt][r] += acc[r];   // y = t + att_out
  }
  lnC(tC, g1, b1, lm);
  __syncthreads();

  // ========== bounce y (bf16) -> A-frags ==========
#pragma unroll
  for (int nt = 0; nt < 8; ++nt)
#pragma unroll
    for (int r = 0; r < 4; ++r)
      Tb[(lg*4+r)*SCB + nt*16+lm] = bf1(tC[nt][r]);
  __syncthreads();
  bf8 yA[4];
#pragma unroll
  for (int kt = 0; kt < 4; ++kt)
    yA[kt] = *(const bf8*)(Tb + lm*SCB + kt*32 + lg*8);
  __syncthreads();

  // ========== FFN1 all 16 tiles -> Ub, ONE barrier, then FFN2 ==========
#pragma unroll
  for (int nt1 = 0; nt1 < 16; ++nt1){
    f32x4 a = zero4;
#pragma unroll
    for (int kt = 0; kt < 4; ++kt){
      U8 bh; bh.q = pW1[(nt1*4+kt)*64 + tid];
      a = MFMA(yA[kt], bh.v, a, 0,0,0);
    }
#pragma unroll
    for (int r = 0; r < 4; ++r)
      Ub[(lg*4+r)*SCUF + nt1*16 + lm] = bf1(silu_f(a[r]));
  }
  __syncthreads();
  f32x4 acc2[8];
#pragma unroll
  for (int nt = 0; nt < 8; ++nt) acc2[nt] = zero4;
#pragma unroll
  for (int kt2 = 0; kt2 < 8; ++kt2){
    bf8 uA = *(const bf8*)(Ub + lm*SCUF + kt2*32 + lg*8);
#pragma unroll
    for (int nt = 0; nt < 8; ++nt){
      U8 bh; bh.q = pW2[(nt*8+kt2)*64 + tid];
      acc2[nt] = MFMA(uA, bh.v, acc2[nt], 0,0,0);
    }
  }

  // ========== residual2, LN2, store ==========
#pragma unroll
  for (int nt = 0; nt < 8; ++nt)
#pragma unroll
    for (int r = 0; r < 4; ++r) tC[nt][r] += acc2[nt][r];
  lnC(tC, g2, b2, lm);

  float* op = out + (size_t)wi*(NHT*MD);
#pragma unroll
  for (int nt = 0; nt < 8; ++nt)
#pragma unroll
    for (int r = 0; r < 4; ++r)
      op[(lg*4+r)*MD + nt*16+lm] = tC[nt][r];
}

extern "C" void kernel_launch(void* const* d_in, const int* in_sizes, int n_in,
                              void* d_out, int out_size, void* d_ws, size_t ws_size,
                              hipStream_t stream) {
  const float* x     = (const float*)d_in[0];
  const float* pos1  = (const float*)d_in[1];
  const float* pos2  = (const float*)d_in[2];
  const float* W_in  = (const float*)d_in[3];
  const float* g_in  = (const float*)d_in[4];
  const float* b_in  = (const float*)d_in[5];
  const float* W_pe  = (const float*)d_in[6];
  const float* W_bias= (const float*)d_in[7];
  const float* Wq    = (const float*)d_in[8];
  const float* bq    = (const float*)d_in[9];
  const float* Wk    = (const float*)d_in[10];
  const float* bk    = (const float*)d_in[11];
  const float* Wv    = (const float*)d_in[12];
  const float* bv    = (const float*)d_in[13];
  const float* Wo    = (const float*)d_in[14];
  const float* bo    = (const float*)d_in[15];
  const float* W1    = (const float*)d_in[16];
  const float* W2    = (const float*)d_in[17];
  const float* g1    = (const float*)d_in[18];
  const float* b1    = (const float*)d_in[19];
  const float* g2    = (const float*)d_in[20];
  const float* b2    = (const float*)d_in[21];
  float* out = (float*)d_out;
  uint4* ws  = (uint4*)d_ws;   // 16384 units (256 KiB) + optional 1024 for W_in

  const int useWin = (ws_size >= (size_t)(16384 + 1024) * 16) ? 1 : 0;

  packw<<<64, 256, 0, stream>>>(Wq, Wk, Wv, Wo, W1, W2, ws);
  if (useWin) packwin<<<4, 256, 0, stream>>>(W_in, ws);

  const int nwin = in_sizes[0] / (NHT * ED);   // 16384
  nha_mfma<<<nwin, 64, 0, stream>>>(x, pos1, pos2, W_in, g_in, b_in, W_pe, W_bias,
                                    bq, bk, bv, bo, g1, b1, g2, b2, ws, useWin, out);
}

// Round 19
// 385.552 us; speedup vs baseline: 1.0031x; 1.0031x over previous
//
#include <hip/hip_runtime.h>
#include <hip/hip_bf16.h>
#include <math.h>

// B=4, N=4096 -> 16384 windows of NHT=16 tokens, MD=128
#define NHT 16
#define MD 128
#define FFD 256
#define NHEAD 4
#define DH 32
#define PED 32
#define ED 64
#define SCALE 0.17677669529663687f
#define SCB 136      // short stride, bf16 [16][128] tiles (272 B rows)
#define SCUF 264     // short stride, full FFN u tile [16][256]

typedef __attribute__((ext_vector_type(8))) short bf8;
typedef __attribute__((ext_vector_type(4))) float f32x4;
union U8 { bf8 v; unsigned short s[8]; uint u[4]; uint4 q; };

#define MFMA __builtin_amdgcn_mfma_f32_16x16x32_bf16

__device__ __forceinline__ unsigned short bf1(float a){
  __hip_bfloat16 h = __float2bfloat16(a);
  return *reinterpret_cast<unsigned short*>(&h);
}
__device__ __forceinline__ float bfh2f(unsigned short s){
  __hip_bfloat16 h = *reinterpret_cast<__hip_bfloat16*>(&s);
  return __bfloat162float(h);
}
// silu with fast hardware reciprocal (v_rcp_f32) instead of IEEE divide
__device__ __forceinline__ float silu_f(float x){
  return x * __builtin_amdgcn_rcpf(1.f + __expf(-x));
}

// VERIFIED (r8/r11/r12/r13/r17): butterfly LN on MFMA C-layout tile
__device__ __forceinline__ void lnC(float (&C)[8][4], const float* __restrict__ g,
                                    const float* __restrict__ b, int lm){
#pragma unroll
  for (int r = 0; r < 4; ++r){
    float s = 0.f, ss = 0.f;
#pragma unroll
    for (int nt = 0; nt < 8; ++nt){ s += C[nt][r]; ss = fmaf(C[nt][r], C[nt][r], ss); }
#pragma unroll
    for (int m = 1; m < 16; m <<= 1){ s += __shfl_xor(s, m); ss += __shfl_xor(ss, m); }
    float mean = s * (1.f/128.f);
    float var  = ss * (1.f/128.f) - mean*mean;
    float rs   = rsqrtf(var + 1e-5f);
#pragma unroll
    for (int nt = 0; nt < 8; ++nt)
      C[nt][r] = fmaf((C[nt][r] - mean) * rs, g[nt*16+lm], b[nt*16+lm]);
  }
}

// ---- weight pre-pack (verified r5-r17): fp32 [K][N] -> bf16 B-frag order; 256 KiB ----
__global__ __launch_bounds__(256)
void packw(const float* __restrict__ Wq, const float* __restrict__ Wk,
           const float* __restrict__ Wv, const float* __restrict__ Wo,
           const float* __restrict__ W1, const float* __restrict__ W2,
           uint4* __restrict__ ws){
  int id = blockIdx.x * 256 + threadIdx.x;   // 16384 total
  const float* W; int KT, N, u; uint4* dst;
  if      (id < 2048) { W = Wq;  KT = 4; N = 128; dst = ws;         u = id;         }
  else if (id < 4096) { W = Wk;  KT = 4; N = 128; dst = ws + 2048;  u = id - 2048;  }
  else if (id < 6144) { W = Wv;  KT = 4; N = 128; dst = ws + 4096;  u = id - 4096;  }
  else if (id < 8192) { W = Wo;  KT = 4; N = 128; dst = ws + 6144;  u = id - 6144;  }
  else if (id < 12288){ W = W1;  KT = 4; N = 256; dst = ws + 8192;  u = id - 8192;  }
  else                { W = W2;  KT = 8; N = 128; dst = ws + 12288; u = id - 12288; }
  int lane = u & 63, tile = u >> 6;
  int kt = tile % KT, nt = tile / KT;
  int kr  = kt*32 + ((lane >> 4) << 3);
  int col = nt*16 + (lane & 15);
  const float* p = W + (size_t)kr * N + col;
  U8 hi;
#pragma unroll
  for (int j = 0; j < 8; ++j) hi.s[j] = bf1(p[(size_t)j * N]);
  dst[u] = hi.q;
}

// W_in pack (verified r12-r17) -> ws + 16384 units; launched only if ws_size allows.
__global__ __launch_bounds__(256)
void packwin(const float* __restrict__ Win, uint4* __restrict__ ws){
  int u = blockIdx.x * 256 + threadIdx.x;   // 1024 total
  int lane = u & 63, tile = u >> 6;
  int kt = tile % 2, nt = tile / 2;
  int kr  = kt*32 + ((lane >> 4) << 3);
  int col = nt*16 + (lane & 15);
  const float* p = Win + (size_t)kr * MD + col;
  U8 hi;
#pragma unroll
  for (int j = 0; j < 8; ++j) hi.s[j] = bf1(p[(size_t)j * MD]);
  ws[16384 + u] = hi.q;
}

// r13/r17 green kernel: single-wave, MFMA attention, dedicated buffers.
// NOTE: this exact LDS map + schedule is correctness-critical — every
// perturbation of it (r14/r15/r16/r18) failed via an un-localized
// layout-sensitive mechanism. Do not modify without a diag harness.
__global__ __launch_bounds__(64)
void nha_mfma(const float* __restrict__ x, const float* __restrict__ pos1,
              const float* __restrict__ pos2,
              const float* __restrict__ W_in,
              const float* __restrict__ g_in, const float* __restrict__ b_in,
              const float* __restrict__ W_pe, const float* __restrict__ W_bias,
              const float* __restrict__ bq, const float* __restrict__ bk,
              const float* __restrict__ bv, const float* __restrict__ bo,
              const float* __restrict__ g1, const float* __restrict__ b1,
              const float* __restrict__ g2, const float* __restrict__ b2,
              const uint4* __restrict__ wsp, int useWin, float* __restrict__ out)
{
  const uint4* pWq  = wsp;
  const uint4* pWk  = wsp + 2048;
  const uint4* pWv  = wsp + 4096;
  const uint4* pWo  = wsp + 6144;
  const uint4* pW1  = wsp + 8192;
  const uint4* pW2  = wsp + 12288;
  const uint4* pWin = wsp + 16384;

  // dedicated, non-aliased buffers
  __shared__ __align__(16) unsigned short Qb[NHT*SCB];   // q rows; later o rows
  __shared__ __align__(16) unsigned short Kb[NHT*SCB];   // k rows
  __shared__ __align__(16) unsigned short Vt[MD*NHT];    // V^T [d=128][ki=16]
  __shared__ __align__(16) unsigned short Pb[NHT*SCB];   // att rows (per-head 32-col slots)
  __shared__ __align__(16) unsigned short Tb[NHT*SCB];   // t bounce; later y bounce
  __shared__ __align__(16) unsigned short Ub[NHT*SCUF];  // FFN u, full width
  __shared__ __align__(16) float Bsm[NHEAD*NHT*NHT];

  const int tid = threadIdx.x;   // one wave per block/window
  const int wi  = blockIdx.x;
  const int lm  = tid & 15;
  const int lg  = tid >> 4;
  const f32x4 zero4 = {0.f,0.f,0.f,0.f};
  const bf8  zero8 = {0,0,0,0,0,0,0,0};

  // ========== Stage A: t = x @ W_in (hi-only) ==========
  bf8 xA[2];
  {
    const float* xp = x + (size_t)wi*1024 + lm*ED + lg*8;
#pragma unroll
    for (int kt = 0; kt < 2; ++kt){
      U8 h;
#pragma unroll
      for (int j = 0; j < 8; ++j) h.s[j] = bf1(xp[kt*32 + j]);
      xA[kt] = h.v;
    }
  }
  float tC[8][4];
#pragma unroll
  for (int nt = 0; nt < 8; ++nt){
    f32x4 acc = zero4;
#pragma unroll
    for (int kt = 0; kt < 2; ++kt){
      U8 w;
      if (useWin){
        w.q = pWin[(nt*2+kt)*64 + tid];
      } else {
        const float* wp = W_in + (size_t)(kt*32 + lg*8)*MD + nt*16 + lm;
#pragma unroll
        for (int j = 0; j < 8; ++j) w.s[j] = bf1(wp[(size_t)j*MD]);
      }
      acc = MFMA(xA[kt], w.v, acc, 0,0,0);
    }
#pragma unroll
    for (int r = 0; r < 4; ++r) tC[nt][r] = acc[r];
  }
  lnC(tC, g_in, b_in, lm);

  // ========== bounce t (bf16) -> A-frags ==========
#pragma unroll
  for (int nt = 0; nt < 8; ++nt)
#pragma unroll
    for (int r = 0; r < 4; ++r)
      Tb[(lg*4+r)*SCB + nt*16+lm] = bf1(tC[nt][r]);
  __syncthreads();
  bf8 tA[4];
#pragma unroll
  for (int kt = 0; kt < 4; ++kt)
    tA[kt] = *(const bf8*)(Tb + lm*SCB + kt*32 + lg*8);
  __syncthreads();

  // ========== Q,K (bf16 rows), V (transposed bf16) = t@W + b ==========
#pragma unroll
  for (int nt = 0; nt < 8; ++nt){
    float bb = bq[nt*16+lm];
    f32x4 acc = {bb,bb,bb,bb};
#pragma unroll
    for (int kt = 0; kt < 4; ++kt){
      U8 bh; bh.q = pWq[(nt*4+kt)*64 + tid];
      acc = MFMA(tA[kt], bh.v, acc, 0,0,0);
    }
#pragma unroll
    for (int r = 0; r < 4; ++r) Qb[(lg*4+r)*SCB + nt*16+lm] = bf1(acc[r]);
  }
#pragma unroll
  for (int nt = 0; nt < 8; ++nt){
    float bb = bk[nt*16+lm];
    f32x4 acc = {bb,bb,bb,bb};
#pragma unroll
    for (int kt = 0; kt < 4; ++kt){
      U8 bh; bh.q = pWk[(nt*4+kt)*64 + tid];
      acc = MFMA(tA[kt], bh.v, acc, 0,0,0);
    }
#pragma unroll
    for (int r = 0; r < 4; ++r) Kb[(lg*4+r)*SCB + nt*16+lm] = bf1(acc[r]);
  }
#pragma unroll
  for (int nt = 0; nt < 8; ++nt){
    float bb = bv[nt*16+lm];
    f32x4 acc = {bb,bb,bb,bb};
#pragma unroll
    for (int kt = 0; kt < 4; ++kt){
      U8 bh; bh.q = pWv[(nt*4+kt)*64 + tid];
      acc = MFMA(tA[kt], bh.v, acc, 0,0,0);
    }
    // V^T store: Vt[d][ki], d = col = nt*16+lm, ki = row = lg*4+r
#pragma unroll
    for (int r = 0; r < 4; ++r) Vt[(nt*16+lm)*NHT + lg*4+r] = bf1(acc[r]);
  }

  // ========== rel-pos bias -> Bsm (fp32, rcpf silu) ==========
  for (int p = tid; p < NHT*NHT; p += 64){
    float p1 = pos1[(size_t)wi*256 + p];
    float p2 = pos2[(size_t)wi*256 + p];
    float a0=0.f, a1=0.f, a2=0.f, a3=0.f;
#pragma unroll
    for (int i = 0; i < PED; ++i){
      float e = fmaf(p1, W_pe[i], p2 * W_pe[PED+i]);
      float sv = silu_f(e);
      a0 = fmaf(sv, W_bias[i*4+0], a0);
      a1 = fmaf(sv, W_bias[i*4+1], a1);
      a2 = fmaf(sv, W_bias[i*4+2], a2);
      a3 = fmaf(sv, W_bias[i*4+3], a3);
    }
    Bsm[0*256 + p] = a0; Bsm[1*256 + p] = a1; Bsm[2*256 + p] = a2; Bsm[3*256 + p] = a3;
  }
  __syncthreads();

  // ========== attention via MFMA (r2 construction, dedicated buffers) ==========
  // S_h = Q_h @ K_h^T : A-frag = Q row lm cols h*32+lg*8 ; B-frag = K row lm (K^T cols)
  bf8 qA[4], kB[4];
#pragma unroll
  for (int h = 0; h < 4; ++h){
    qA[h] = *(const bf8*)(Qb + lm*SCB + h*32 + lg*8);
    kB[h] = *(const bf8*)(Kb + lm*SCB + h*32 + lg*8);
  }
#pragma unroll
  for (int h = 0; h < 4; ++h){
    f32x4 s = MFMA(qA[h], kB[h], zero4, 0,0,0);
    // softmax over ki (= lm lanes), rows qi = lg*4+r — lnC's verified butterfly
#pragma unroll
    for (int r = 0; r < 4; ++r){
      float v = fmaf(s[r], SCALE, Bsm[h*256 + (lg*4+r)*16 + lm]);
      float mx = v;
#pragma unroll
      for (int m = 1; m < 16; m <<= 1) mx = fmaxf(mx, __shfl_xor(mx, m));
      float e = __expf(v - mx);
      float sm = e;
#pragma unroll
      for (int m = 1; m < 16; m <<= 1) sm += __shfl_xor(sm, m);
      Pb[(lg*4+r)*SCB + h*32 + lm] = bf1(e * __builtin_amdgcn_rcpf(sm));
    }
  }
  __syncthreads();

  // PV: O_h = P_h @ V_h  (K=32, upper 16 k zeroed via A)
#pragma unroll
  for (int h = 0; h < 4; ++h){
    bf8 aP = *(const bf8*)(Pb + lm*SCB + h*32 + lg*8);
    if (tid >= 32) aP = zero8;        // k = lg*8+j >= 16 -> zero contribution
#pragma unroll
    for (int n2 = 0; n2 < 2; ++n2){
      bf8 vB = *(const bf8*)(Vt + (h*32 + n2*16 + lm)*NHT + (lg & 1)*8);
      if (tid >= 32) vB = zero8;
      f32x4 o = MFMA(aP, vB, zero4, 0,0,0);
      // o rows over Qb (q fully consumed into qA regs)
#pragma unroll
      for (int r = 0; r < 4; ++r)
        Qb[(lg*4+r)*SCB + h*32 + n2*16 + lm] = bf1(o[r]);
    }
  }
  __syncthreads();

  // ========== att_out = o@Wo + bo, residual, LN1 ==========
  bf8 oA[4];
#pragma unroll
  for (int kt = 0; kt < 4; ++kt)
    oA[kt] = *(const bf8*)(Qb + lm*SCB + kt*32 + lg*8);
#pragma unroll
  for (int nt = 0; nt < 8; ++nt){
    float bb = bo[nt*16+lm];
    f32x4 acc = {bb,bb,bb,bb};
#pragma unroll
    for (int kt = 0; kt < 4; ++kt){
      U8 bh; bh.q = pWo[(nt*4+kt)*64 + tid];
      acc = MFMA(oA[kt], bh.v, acc, 0,0,0);
    }
#pragma unroll
    for (int r = 0; r < 4; ++r) tC[nt][r] += acc[r];   // y = t + att_out
  }
  lnC(tC, g1, b1, lm);
  __syncthreads();

  // ========== bounce y (bf16) -> A-frags ==========
#pragma unroll
  for (int nt = 0; nt < 8; ++nt)
#pragma unroll
    for (int r = 0; r < 4; ++r)
      Tb[(lg*4+r)*SCB + nt*16+lm] = bf1(tC[nt][r]);
  __syncthreads();
  bf8 yA[4];
#pragma unroll
  for (int kt = 0; kt < 4; ++kt)
    yA[kt] = *(const bf8*)(Tb + lm*SCB + kt*32 + lg*8);
  __syncthreads();

  // ========== FFN1 all 16 tiles -> Ub, ONE barrier, then FFN2 ==========
#pragma unroll
  for (int nt1 = 0; nt1 < 16; ++nt1){
    f32x4 a = zero4;
#pragma unroll
    for (int kt = 0; kt < 4; ++kt){
      U8 bh; bh.q = pW1[(nt1*4+kt)*64 + tid];
      a = MFMA(yA[kt], bh.v, a, 0,0,0);
    }
#pragma unroll
    for (int r = 0; r < 4; ++r)
      Ub[(lg*4+r)*SCUF + nt1*16 + lm] = bf1(silu_f(a[r]));
  }
  __syncthreads();
  f32x4 acc2[8];
#pragma unroll
  for (int nt = 0; nt < 8; ++nt) acc2[nt] = zero4;
#pragma unroll
  for (int kt2 = 0; kt2 < 8; ++kt2){
    bf8 uA = *(const bf8*)(Ub + lm*SCUF + kt2*32 + lg*8);
#pragma unroll
    for (int nt = 0; nt < 8; ++nt){
      U8 bh; bh.q = pW2[(nt*8+kt2)*64 + tid];
      acc2[nt] = MFMA(uA, bh.v, acc2[nt], 0,0,0);
    }
  }

  // ========== residual2, LN2, store ==========
#pragma unroll
  for (int nt = 0; nt < 8; ++nt)
#pragma unroll
    for (int r = 0; r < 4; ++r) tC[nt][r] += acc2[nt][r];
  lnC(tC, g2, b2, lm);

  float* op = out + (size_t)wi*(NHT*MD);
#pragma unroll
  for (int nt = 0; nt < 8; ++nt)
#pragma unroll
    for (int r = 0; r < 4; ++r)
      op[(lg*4+r)*MD + nt*16+lm] = tC[nt][r];
}

extern "C" void kernel_launch(void* const* d_in, const int* in_sizes, int n_in,
                              void* d_out, int out_size, void* d_ws, size_t ws_size,
                              hipStream_t stream) {
  const float* x     = (const float*)d_in[0];
  const float* pos1  = (const float*)d_in[1];
  const float* pos2  = (const float*)d_in[2];
  const float* W_in  = (const float*)d_in[3];
  const float* g_in  = (const float*)d_in[4];
  const float* b_in  = (const float*)d_in[5];
  const float* W_pe  = (const float*)d_in[6];
  const float* W_bias= (const float*)d_in[7];
  const float* Wq    = (const float*)d_in[8];
  const float* bq    = (const float*)d_in[9];
  const float* Wk    = (const float*)d_in[10];
  const float* bk    = (const float*)d_in[11];
  const float* Wv    = (const float*)d_in[12];
  const float* bv    = (const float*)d_in[13];
  const float* Wo    = (const float*)d_in[14];
  const float* bo    = (const float*)d_in[15];
  const float* W1    = (const float*)d_in[16];
  const float* W2    = (const float*)d_in[17];
  const float* g1    = (const float*)d_in[18];
  const float* b1    = (const float*)d_in[19];
  const float* g2    = (const float*)d_in[20];
  const float* b2    = (const float*)d_in[21];
  float* out = (float*)d_out;
  uint4* ws  = (uint4*)d_ws;   // 16384 units (256 KiB) + optional 1024 for W_in

  const int useWin = (ws_size >= (size_t)(16384 + 1024) * 16) ? 1 : 0;

  packw<<<64, 256, 0, stream>>>(Wq, Wk, Wv, Wo, W1, W2, ws);
  if (useWin) packwin<<<4, 256, 0, stream>>>(W_in, ws);

  const int nwin = in_sizes[0] / (NHT * ED);   // 16384
  nha_mfma<<<nwin, 64, 0, stream>>>(x, pos1, pos2, W_in, g_in, b_in, W_pe, W_bias,
                                    bq, bk, bv, bo, g1, b1, g2, b2, ws, useWin, out);
}

// Round 20
// 382.623 us; speedup vs baseline: 1.0108x; 1.0077x over previous
//
#include <hip/hip_runtime.h>
#include <hip/hip_bf16.h>
#include <math.h>

// B=4, N=4096 -> 16384 windows of NHT=16 tokens, MD=128
#define NHT 16
#define MD 128
#define FFD 256
#define NHEAD 4
#define DH 32
#define PED 32
#define ED 64
#define SCALE 0.17677669529663687f
#define SCB 136      // short stride, bf16 [16][128] tiles (272 B rows)
#define SCUF 264     // short stride, full FFN u tile [16][256]

typedef __attribute__((ext_vector_type(8))) short bf8;
typedef __attribute__((ext_vector_type(4))) float f32x4;
union U8 { bf8 v; unsigned short s[8]; uint u[4]; uint4 q; };

#define MFMA __builtin_amdgcn_mfma_f32_16x16x32_bf16

__device__ __forceinline__ unsigned short bf1(float a){
  __hip_bfloat16 h = __float2bfloat16(a);
  return *reinterpret_cast<unsigned short*>(&h);
}
__device__ __forceinline__ float bfh2f(unsigned short s){
  __hip_bfloat16 h = *reinterpret_cast<__hip_bfloat16*>(&s);
  return __bfloat162float(h);
}
// silu with fast hardware reciprocal (v_rcp_f32)
__device__ __forceinline__ float silu_f(float x){
  return x * __builtin_amdgcn_rcpf(1.f + __expf(-x));
}

// VERIFIED (r8-r19): butterfly LN on MFMA C-layout tile
__device__ __forceinline__ void lnC(float (&C)[8][4], const float* __restrict__ g,
                                    const float* __restrict__ b, int lm){
#pragma unroll
  for (int r = 0; r < 4; ++r){
    float s = 0.f, ss = 0.f;
#pragma unroll
    for (int nt = 0; nt < 8; ++nt){ s += C[nt][r]; ss = fmaf(C[nt][r], C[nt][r], ss); }
#pragma unroll
    for (int m = 1; m < 16; m <<= 1){ s += __shfl_xor(s, m); ss += __shfl_xor(ss, m); }
    float mean = s * (1.f/128.f);
    float var  = ss * (1.f/128.f) - mean*mean;
    float rs   = rsqrtf(var + 1e-5f);
#pragma unroll
    for (int nt = 0; nt < 8; ++nt)
      C[nt][r] = fmaf((C[nt][r] - mean) * rs, g[nt*16+lm], b[nt*16+lm]);
  }
}

// ---- weight pre-pack (verified r5-r19): fp32 [K][N] -> bf16 B-frag order; 256 KiB ----
__global__ __launch_bounds__(256)
void packw(const float* __restrict__ Wq, const float* __restrict__ Wk,
           const float* __restrict__ Wv, const float* __restrict__ Wo,
           const float* __restrict__ W1, const float* __restrict__ W2,
           uint4* __restrict__ ws){
  int id = blockIdx.x * 256 + threadIdx.x;   // 16384 total
  const float* W; int KT, N, u; uint4* dst;
  if      (id < 2048) { W = Wq;  KT = 4; N = 128; dst = ws;         u = id;         }
  else if (id < 4096) { W = Wk;  KT = 4; N = 128; dst = ws + 2048;  u = id - 2048;  }
  else if (id < 6144) { W = Wv;  KT = 4; N = 128; dst = ws + 4096;  u = id - 4096;  }
  else if (id < 8192) { W = Wo;  KT = 4; N = 128; dst = ws + 6144;  u = id - 6144;  }
  else if (id < 12288){ W = W1;  KT = 4; N = 256; dst = ws + 8192;  u = id - 8192;  }
  else                { W = W2;  KT = 8; N = 128; dst = ws + 12288; u = id - 12288; }
  int lane = u & 63, tile = u >> 6;
  int kt = tile % KT, nt = tile / KT;
  int kr  = kt*32 + ((lane >> 4) << 3);
  int col = nt*16 + (lane & 15);
  const float* p = W + (size_t)kr * N + col;
  U8 hi;
#pragma unroll
  for (int j = 0; j < 8; ++j) hi.s[j] = bf1(p[(size_t)j * N]);
  dst[u] = hi.q;
}

// W_in pack (verified r12-r19) -> ws + 16384 units; launched only if ws_size allows.
__global__ __launch_bounds__(256)
void packwin(const float* __restrict__ Win, uint4* __restrict__ ws){
  int u = blockIdx.x * 256 + threadIdx.x;   // 1024 total
  int lane = u & 63, tile = u >> 6;
  int kt = tile % 2, nt = tile / 2;
  int kr  = kt*32 + ((lane >> 4) << 3);
  int col = nt*16 + (lane & 15);
  const float* p = Win + (size_t)kr * MD + col;
  U8 hi;
#pragma unroll
  for (int j = 0; j < 8; ++j) hi.s[j] = bf1(p[(size_t)j * MD]);
  ws[16384 + u] = hi.q;
}

// r17 green kernel + pairwise weight-frag prefetch (pure issue-order change:
// same LDS map, same wave structure, same arithmetic order).
__global__ __launch_bounds__(64)
void nha_mfma(const float* __restrict__ x, const float* __restrict__ pos1,
              const float* __restrict__ pos2,
              const float* __restrict__ W_in,
              const float* __restrict__ g_in, const float* __restrict__ b_in,
              const float* __restrict__ W_pe, const float* __restrict__ W_bias,
              const float* __restrict__ bq, const float* __restrict__ bk,
              const float* __restrict__ bv, const float* __restrict__ bo,
              const float* __restrict__ g1, const float* __restrict__ b1,
              const float* __restrict__ g2, const float* __restrict__ b2,
              const uint4* __restrict__ wsp, int useWin, float* __restrict__ out)
{
  const uint4* pWq  = wsp;
  const uint4* pWk  = wsp + 2048;
  const uint4* pWv  = wsp + 4096;
  const uint4* pWo  = wsp + 6144;
  const uint4* pW1  = wsp + 8192;
  const uint4* pW2  = wsp + 12288;
  const uint4* pWin = wsp + 16384;

  // dedicated, non-aliased buffers — byte-identical map to r17/r19 (proven green)
  __shared__ __align__(16) unsigned short Qb[NHT*SCB];   // q rows; later o rows
  __shared__ __align__(16) unsigned short Kb[NHT*SCB];   // k rows
  __shared__ __align__(16) unsigned short Vt[MD*NHT];    // V^T [d=128][ki=16]
  __shared__ __align__(16) unsigned short Pb[NHT*SCB];   // att rows (per-head 32-col slots)
  __shared__ __align__(16) unsigned short Tb[NHT*SCB];   // t bounce; later y bounce
  __shared__ __align__(16) unsigned short Ub[NHT*SCUF];  // FFN u, full width
  __shared__ __align__(16) float Bsm[NHEAD*NHT*NHT];

  const int tid = threadIdx.x;   // one wave per block/window
  const int wi  = blockIdx.x;
  const int lm  = tid & 15;
  const int lg  = tid >> 4;
  const f32x4 zero4 = {0.f,0.f,0.f,0.f};
  const bf8  zero8 = {0,0,0,0,0,0,0,0};

  // ========== Stage A: t = x @ W_in (hi-only) ==========
  bf8 xA[2];
  {
    const float* xp = x + (size_t)wi*1024 + lm*ED + lg*8;
#pragma unroll
    for (int kt = 0; kt < 2; ++kt){
      U8 h;
#pragma unroll
      for (int j = 0; j < 8; ++j) h.s[j] = bf1(xp[kt*32 + j]);
      xA[kt] = h.v;
    }
  }
  float tC[8][4];
#pragma unroll
  for (int nt = 0; nt < 8; ++nt){
    f32x4 acc = zero4;
#pragma unroll
    for (int kt = 0; kt < 2; ++kt){
      U8 w;
      if (useWin){
        w.q = pWin[(nt*2+kt)*64 + tid];
      } else {
        const float* wp = W_in + (size_t)(kt*32 + lg*8)*MD + nt*16 + lm;
#pragma unroll
        for (int j = 0; j < 8; ++j) w.s[j] = bf1(wp[(size_t)j*MD]);
      }
      acc = MFMA(xA[kt], w.v, acc, 0,0,0);
    }
#pragma unroll
    for (int r = 0; r < 4; ++r) tC[nt][r] = acc[r];
  }
  lnC(tC, g_in, b_in, lm);

  // ========== bounce t (bf16) -> A-frags ==========
#pragma unroll
  for (int nt = 0; nt < 8; ++nt)
#pragma unroll
    for (int r = 0; r < 4; ++r)
      Tb[(lg*4+r)*SCB + nt*16+lm] = bf1(tC[nt][r]);
  __syncthreads();
  bf8 tA[4];
#pragma unroll
  for (int kt = 0; kt < 4; ++kt)
    tA[kt] = *(const bf8*)(Tb + lm*SCB + kt*32 + lg*8);
  __syncthreads();

  // ========== Q,K (bf16 rows), V (transposed bf16) = t@W + b — pairwise prefetch ==========
#pragma unroll
  for (int nt = 0; nt < 8; nt += 2){
    U8 w0[4], w1[4];
#pragma unroll
    for (int kt = 0; kt < 4; ++kt) w0[kt].q = pWq[((nt+0)*4+kt)*64 + tid];
#pragma unroll
    for (int kt = 0; kt < 4; ++kt) w1[kt].q = pWq[((nt+1)*4+kt)*64 + tid];
    float b0 = bq[(nt+0)*16+lm], b1v = bq[(nt+1)*16+lm];
    f32x4 a0 = {b0,b0,b0,b0}, a1 = {b1v,b1v,b1v,b1v};
#pragma unroll
    for (int kt = 0; kt < 4; ++kt) a0 = MFMA(tA[kt], w0[kt].v, a0, 0,0,0);
#pragma unroll
    for (int kt = 0; kt < 4; ++kt) a1 = MFMA(tA[kt], w1[kt].v, a1, 0,0,0);
#pragma unroll
    for (int r = 0; r < 4; ++r){
      Qb[(lg*4+r)*SCB + (nt+0)*16+lm] = bf1(a0[r]);
      Qb[(lg*4+r)*SCB + (nt+1)*16+lm] = bf1(a1[r]);
    }
  }
#pragma unroll
  for (int nt = 0; nt < 8; nt += 2){
    U8 w0[4], w1[4];
#pragma unroll
    for (int kt = 0; kt < 4; ++kt) w0[kt].q = pWk[((nt+0)*4+kt)*64 + tid];
#pragma unroll
    for (int kt = 0; kt < 4; ++kt) w1[kt].q = pWk[((nt+1)*4+kt)*64 + tid];
    float b0 = bk[(nt+0)*16+lm], b1v = bk[(nt+1)*16+lm];
    f32x4 a0 = {b0,b0,b0,b0}, a1 = {b1v,b1v,b1v,b1v};
#pragma unroll
    for (int kt = 0; kt < 4; ++kt) a0 = MFMA(tA[kt], w0[kt].v, a0, 0,0,0);
#pragma unroll
    for (int kt = 0; kt < 4; ++kt) a1 = MFMA(tA[kt], w1[kt].v, a1, 0,0,0);
#pragma unroll
    for (int r = 0; r < 4; ++r){
      Kb[(lg*4+r)*SCB + (nt+0)*16+lm] = bf1(a0[r]);
      Kb[(lg*4+r)*SCB + (nt+1)*16+lm] = bf1(a1[r]);
    }
  }
#pragma unroll
  for (int nt = 0; nt < 8; nt += 2){
    U8 w0[4], w1[4];
#pragma unroll
    for (int kt = 0; kt < 4; ++kt) w0[kt].q = pWv[((nt+0)*4+kt)*64 + tid];
#pragma unroll
    for (int kt = 0; kt < 4; ++kt) w1[kt].q = pWv[((nt+1)*4+kt)*64 + tid];
    float b0 = bv[(nt+0)*16+lm], b1v = bv[(nt+1)*16+lm];
    f32x4 a0 = {b0,b0,b0,b0}, a1 = {b1v,b1v,b1v,b1v};
#pragma unroll
    for (int kt = 0; kt < 4; ++kt) a0 = MFMA(tA[kt], w0[kt].v, a0, 0,0,0);
#pragma unroll
    for (int kt = 0; kt < 4; ++kt) a1 = MFMA(tA[kt], w1[kt].v, a1, 0,0,0);
    // V^T store: Vt[d][ki], d = col = nt*16+lm, ki = row = lg*4+r
#pragma unroll
    for (int r = 0; r < 4; ++r){
      Vt[((nt+0)*16+lm)*NHT + lg*4+r] = bf1(a0[r]);
      Vt[((nt+1)*16+lm)*NHT + lg*4+r] = bf1(a1[r]);
    }
  }

  // ========== rel-pos bias -> Bsm (fp32, rcpf silu) ==========
  for (int p = tid; p < NHT*NHT; p += 64){
    float p1 = pos1[(size_t)wi*256 + p];
    float p2 = pos2[(size_t)wi*256 + p];
    float a0=0.f, a1=0.f, a2=0.f, a3=0.f;
#pragma unroll
    for (int i = 0; i < PED; ++i){
      float e = fmaf(p1, W_pe[i], p2 * W_pe[PED+i]);
      float sv = silu_f(e);
      a0 = fmaf(sv, W_bias[i*4+0], a0);
      a1 = fmaf(sv, W_bias[i*4+1], a1);
      a2 = fmaf(sv, W_bias[i*4+2], a2);
      a3 = fmaf(sv, W_bias[i*4+3], a3);
    }
    Bsm[0*256 + p] = a0; Bsm[1*256 + p] = a1; Bsm[2*256 + p] = a2; Bsm[3*256 + p] = a3;
  }
  __syncthreads();

  // ========== attention via MFMA (r13/r17-verified construction) ==========
  bf8 qA[4], kB[4];
#pragma unroll
  for (int h = 0; h < 4; ++h){
    qA[h] = *(const bf8*)(Qb + lm*SCB + h*32 + lg*8);
    kB[h] = *(const bf8*)(Kb + lm*SCB + h*32 + lg*8);
  }
#pragma unroll
  for (int h = 0; h < 4; ++h){
    f32x4 s = MFMA(qA[h], kB[h], zero4, 0,0,0);
#pragma unroll
    for (int r = 0; r < 4; ++r){
      float v = fmaf(s[r], SCALE, Bsm[h*256 + (lg*4+r)*16 + lm]);
      float mx = v;
#pragma unroll
      for (int m = 1; m < 16; m <<= 1) mx = fmaxf(mx, __shfl_xor(mx, m));
      float e = __expf(v - mx);
      float sm = e;
#pragma unroll
      for (int m = 1; m < 16; m <<= 1) sm += __shfl_xor(sm, m);
      Pb[(lg*4+r)*SCB + h*32 + lm] = bf1(e * __builtin_amdgcn_rcpf(sm));
    }
  }
  __syncthreads();

  // PV: O_h = P_h @ V_h  (K=32, upper 16 k zeroed via A)
#pragma unroll
  for (int h = 0; h < 4; ++h){
    bf8 aP = *(const bf8*)(Pb + lm*SCB + h*32 + lg*8);
    if (tid >= 32) aP = zero8;        // k = lg*8+j >= 16 -> zero contribution
#pragma unroll
    for (int n2 = 0; n2 < 2; ++n2){
      bf8 vB = *(const bf8*)(Vt + (h*32 + n2*16 + lm)*NHT + (lg & 1)*8);
      if (tid >= 32) vB = zero8;
      f32x4 o = MFMA(aP, vB, zero4, 0,0,0);
#pragma unroll
      for (int r = 0; r < 4; ++r)
        Qb[(lg*4+r)*SCB + h*32 + n2*16 + lm] = bf1(o[r]);
    }
  }
  __syncthreads();

  // ========== att_out = o@Wo + bo, residual, LN1 — pairwise prefetch ==========
  bf8 oA[4];
#pragma unroll
  for (int kt = 0; kt < 4; ++kt)
    oA[kt] = *(const bf8*)(Qb + lm*SCB + kt*32 + lg*8);
#pragma unroll
  for (int nt = 0; nt < 8; nt += 2){
    U8 w0[4], w1[4];
#pragma unroll
    for (int kt = 0; kt < 4; ++kt) w0[kt].q = pWo[((nt+0)*4+kt)*64 + tid];
#pragma unroll
    for (int kt = 0; kt < 4; ++kt) w1[kt].q = pWo[((nt+1)*4+kt)*64 + tid];
    float b0 = bo[(nt+0)*16+lm], b1v = bo[(nt+1)*16+lm];
    f32x4 a0 = {b0,b0,b0,b0}, a1 = {b1v,b1v,b1v,b1v};
#pragma unroll
    for (int kt = 0; kt < 4; ++kt) a0 = MFMA(oA[kt], w0[kt].v, a0, 0,0,0);
#pragma unroll
    for (int kt = 0; kt < 4; ++kt) a1 = MFMA(oA[kt], w1[kt].v, a1, 0,0,0);
#pragma unroll
    for (int r = 0; r < 4; ++r){
      tC[nt+0][r] += a0[r];
      tC[nt+1][r] += a1[r];
    }
  }
  lnC(tC, g1, b1, lm);
  __syncthreads();

  // ========== bounce y (bf16) -> A-frags ==========
#pragma unroll
  for (int nt = 0; nt < 8; ++nt)
#pragma unroll
    for (int r = 0; r < 4; ++r)
      Tb[(lg*4+r)*SCB + nt*16+lm] = bf1(tC[nt][r]);
  __syncthreads();
  bf8 yA[4];
#pragma unroll
  for (int kt = 0; kt < 4; ++kt)
    yA[kt] = *(const bf8*)(Tb + lm*SCB + kt*32 + lg*8);
  __syncthreads();

  // ========== FFN1 all 16 tiles (pairwise prefetch) -> Ub, ONE barrier, FFN2 ==========
#pragma unroll
  for (int nt1 = 0; nt1 < 16; nt1 += 2){
    U8 w0[4], w1[4];
#pragma unroll
    for (int kt = 0; kt < 4; ++kt) w0[kt].q = pW1[((nt1+0)*4+kt)*64 + tid];
#pragma unroll
    for (int kt = 0; kt < 4; ++kt) w1[kt].q = pW1[((nt1+1)*4+kt)*64 + tid];
    f32x4 a0 = zero4, a1 = zero4;
#pragma unroll
    for (int kt = 0; kt < 4; ++kt) a0 = MFMA(yA[kt], w0[kt].v, a0, 0,0,0);
#pragma unroll
    for (int kt = 0; kt < 4; ++kt) a1 = MFMA(yA[kt], w1[kt].v, a1, 0,0,0);
#pragma unroll
    for (int r = 0; r < 4; ++r){
      Ub[(lg*4+r)*SCUF + (nt1+0)*16 + lm] = bf1(silu_f(a0[r]));
      Ub[(lg*4+r)*SCUF + (nt1+1)*16 + lm] = bf1(silu_f(a1[r]));
    }
  }
  __syncthreads();
  f32x4 acc2[8];
#pragma unroll
  for (int nt = 0; nt < 8; ++nt) acc2[nt] = zero4;
#pragma unroll
  for (int kt2 = 0; kt2 < 8; ++kt2){
    bf8 uA = *(const bf8*)(Ub + lm*SCUF + kt2*32 + lg*8);
    U8 wv2[8];
#pragma unroll
    for (int nt = 0; nt < 8; ++nt) wv2[nt].q = pW2[(nt*8+kt2)*64 + tid];
#pragma unroll
    for (int nt = 0; nt < 8; ++nt)
      acc2[nt] = MFMA(uA, wv2[nt].v, acc2[nt], 0,0,0);
  }

  // ========== residual2, LN2, store ==========
#pragma unroll
  for (int nt = 0; nt < 8; ++nt)
#pragma unroll
    for (int r = 0; r < 4; ++r) tC[nt][r] += acc2[nt][r];
  lnC(tC, g2, b2, lm);

  float* op = out + (size_t)wi*(NHT*MD);
#pragma unroll
  for (int nt = 0; nt < 8; ++nt)
#pragma unroll
    for (int r = 0; r < 4; ++r)
      op[(lg*4+r)*MD + nt*16+lm] = tC[nt][r];
}

extern "C" void kernel_launch(void* const* d_in, const int* in_sizes, int n_in,
                              void* d_out, int out_size, void* d_ws, size_t ws_size,
                              hipStream_t stream) {
  const float* x     = (const float*)d_in[0];
  const float* pos1  = (const float*)d_in[1];
  const float* pos2  = (const float*)d_in[2];
  const float* W_in  = (const float*)d_in[3];
  const float* g_in  = (const float*)d_in[4];
  const float* b_in  = (const float*)d_in[5];
  const float* W_pe  = (const float*)d_in[6];
  const float* W_bias= (const float*)d_in[7];
  const float* Wq    = (const float*)d_in[8];
  const float* bq    = (const float*)d_in[9];
  const float* Wk    = (const float*)d_in[10];
  const float* bk    = (const float*)d_in[11];
  const float* Wv    = (const float*)d_in[12];
  const float* bv    = (const float*)d_in[13];
  const float* Wo    = (const float*)d_in[14];
  const float* bo    = (const float*)d_in[15];
  const float* W1    = (const float*)d_in[16];
  const float* W2    = (const float*)d_in[17];
  const float* g1    = (const float*)d_in[18];
  const float* b1    = (const float*)d_in[19];
  const float* g2    = (const float*)d_in[20];
  const float* b2    = (const float*)d_in[21];
  float* out = (float*)d_out;
  uint4* ws  = (uint4*)d_ws;   // 16384 units (256 KiB) + optional 1024 for W_in

  const int useWin = (ws_size >= (size_t)(16384 + 1024) * 16) ? 1 : 0;

  packw<<<64, 256, 0, stream>>>(Wq, Wk, Wv, Wo, W1, W2, ws);
  if (useWin) packwin<<<4, 256, 0, stream>>>(W_in, ws);

  const int nwin = in_sizes[0] / (NHT * ED);   // 16384
  nha_mfma<<<nwin, 64, 0, stream>>>(x, pos1, pos2, W_in, g_in, b_in, W_pe, W_bias,
                                    bq, bk, bv, bo, g1, b1, g2, b2, ws, useWin, out);
}

// Round 21
// 375.424 us; speedup vs baseline: 1.0302x; 1.0192x over previous
//
#include <hip/hip_runtime.h>
#include <hip/hip_bf16.h>
#include <math.h>

// B=4, N=4096 -> 16384 windows of NHT=16 tokens, MD=128
#define NHT 16
#define MD 128
#define FFD 256
#define NHEAD 4
#define DH 32
#define PED 32
#define ED 64
#define SCALE 0.17677669529663687f
#define SCB 136      // short stride, bf16 [16][128] tiles (272 B rows)
#define SCUF 264     // short stride, full FFN u tile [16][256]

typedef __attribute__((ext_vector_type(8))) short bf8;
typedef __attribute__((ext_vector_type(4))) float f32x4;
union U8 { bf8 v; unsigned short s[8]; uint u[4]; uint4 q; };

#define MFMA __builtin_amdgcn_mfma_f32_16x16x32_bf16

__device__ __forceinline__ unsigned short bf1(float a){
  __hip_bfloat16 h = __float2bfloat16(a);
  return *reinterpret_cast<unsigned short*>(&h);
}
__device__ __forceinline__ float bfh2f(unsigned short s){
  __hip_bfloat16 h = *reinterpret_cast<__hip_bfloat16*>(&s);
  return __bfloat162float(h);
}
// silu with fast hardware reciprocal (v_rcp_f32)
__device__ __forceinline__ float silu_f(float x){
  return x * __builtin_amdgcn_rcpf(1.f + __expf(-x));
}

// VERIFIED (r8-r20): butterfly LN on MFMA C-layout tile
__device__ __forceinline__ void lnC(float (&C)[8][4], const float* __restrict__ g,
                                    const float* __restrict__ b, int lm){
#pragma unroll
  for (int r = 0; r < 4; ++r){
    float s = 0.f, ss = 0.f;
#pragma unroll
    for (int nt = 0; nt < 8; ++nt){ s += C[nt][r]; ss = fmaf(C[nt][r], C[nt][r], ss); }
#pragma unroll
    for (int m = 1; m < 16; m <<= 1){ s += __shfl_xor(s, m); ss += __shfl_xor(ss, m); }
    float mean = s * (1.f/128.f);
    float var  = ss * (1.f/128.f) - mean*mean;
    float rs   = rsqrtf(var + 1e-5f);
#pragma unroll
    for (int nt = 0; nt < 8; ++nt)
      C[nt][r] = fmaf((C[nt][r] - mean) * rs, g[nt*16+lm], b[nt*16+lm]);
  }
}

// ---- weight pre-pack (verified r5-r20): fp32 [K][N] -> bf16 B-frag order; 256 KiB ----
__global__ __launch_bounds__(256)
void packw(const float* __restrict__ Wq, const float* __restrict__ Wk,
           const float* __restrict__ Wv, const float* __restrict__ Wo,
           const float* __restrict__ W1, const float* __restrict__ W2,
           uint4* __restrict__ ws){
  int id = blockIdx.x * 256 + threadIdx.x;   // 16384 total
  const float* W; int KT, N, u; uint4* dst;
  if      (id < 2048) { W = Wq;  KT = 4; N = 128; dst = ws;         u = id;         }
  else if (id < 4096) { W = Wk;  KT = 4; N = 128; dst = ws + 2048;  u = id - 2048;  }
  else if (id < 6144) { W = Wv;  KT = 4; N = 128; dst = ws + 4096;  u = id - 4096;  }
  else if (id < 8192) { W = Wo;  KT = 4; N = 128; dst = ws + 6144;  u = id - 6144;  }
  else if (id < 12288){ W = W1;  KT = 4; N = 256; dst = ws + 8192;  u = id - 8192;  }
  else                { W = W2;  KT = 8; N = 128; dst = ws + 12288; u = id - 12288; }
  int lane = u & 63, tile = u >> 6;
  int kt = tile % KT, nt = tile / KT;
  int kr  = kt*32 + ((lane >> 4) << 3);
  int col = nt*16 + (lane & 15);
  const float* p = W + (size_t)kr * N + col;
  U8 hi;
#pragma unroll
  for (int j = 0; j < 8; ++j) hi.s[j] = bf1(p[(size_t)j * N]);
  dst[u] = hi.q;
}

// W_in pack (verified r12-r20) -> ws + 16384 units; launched only if ws_size allows.
__global__ __launch_bounds__(256)
void packwin(const float* __restrict__ Win, uint4* __restrict__ ws){
  int u = blockIdx.x * 256 + threadIdx.x;   // 1024 total
  int lane = u & 63, tile = u >> 6;
  int kt = tile % 2, nt = tile / 2;
  int kr  = kt*32 + ((lane >> 4) << 3);
  int col = nt*16 + (lane & 15);
  const float* p = Win + (size_t)kr * MD + col;
  U8 hi;
#pragma unroll
  for (int j = 0; j < 8; ++j) hi.s[j] = bf1(p[(size_t)j * MD]);
  ws[16384 + u] = hi.q;
}

// ---- bias precompute: rel-pos MLP per window into that window's out region ----
// out[wi*2048 + h*256 + p] holds bias[h][qi][ki]; read by nha_mfma (same block's
// window), then fully overwritten by the final store. Verbatim arithmetic from
// the r20 in-kernel loop (bit-identical values).
__global__ __launch_bounds__(64)
void biask(const float* __restrict__ pos1, const float* __restrict__ pos2,
           const float* __restrict__ W_pe, const float* __restrict__ W_bias,
           float* __restrict__ out){
  const int wi  = blockIdx.x;
  const int tid = threadIdx.x;
  for (int p = tid; p < NHT*NHT; p += 64){
    float p1 = pos1[(size_t)wi*256 + p];
    float p2 = pos2[(size_t)wi*256 + p];
    float a0=0.f, a1=0.f, a2=0.f, a3=0.f;
#pragma unroll
    for (int i = 0; i < PED; ++i){
      float e = fmaf(p1, W_pe[i], p2 * W_pe[PED+i]);
      float sv = silu_f(e);
      a0 = fmaf(sv, W_bias[i*4+0], a0);
      a1 = fmaf(sv, W_bias[i*4+1], a1);
      a2 = fmaf(sv, W_bias[i*4+2], a2);
      a3 = fmaf(sv, W_bias[i*4+3], a3);
    }
    float* bp = out + (size_t)wi*2048;
    bp[0*256 + p] = a0; bp[1*256 + p] = a1;
    bp[2*256 + p] = a2; bp[3*256 + p] = a3;
  }
}

// r20 green kernel (prefetch variant); bias phase now loads precomputed values.
// LDS map and wave structure byte-identical to r17/r19/r20 (proven green).
__global__ __launch_bounds__(64)
void nha_mfma(const float* __restrict__ x,
              const float* __restrict__ W_in,
              const float* __restrict__ g_in, const float* __restrict__ b_in,
              const float* __restrict__ bq, const float* __restrict__ bk,
              const float* __restrict__ bv, const float* __restrict__ bo,
              const float* __restrict__ g1, const float* __restrict__ b1,
              const float* __restrict__ g2, const float* __restrict__ b2,
              const uint4* __restrict__ wsp, int useWin, float* __restrict__ out)
{
  const uint4* pWq  = wsp;
  const uint4* pWk  = wsp + 2048;
  const uint4* pWv  = wsp + 4096;
  const uint4* pWo  = wsp + 6144;
  const uint4* pW1  = wsp + 8192;
  const uint4* pW2  = wsp + 12288;
  const uint4* pWin = wsp + 16384;

  // dedicated, non-aliased buffers — byte-identical map to r17/r19/r20
  __shared__ __align__(16) unsigned short Qb[NHT*SCB];   // q rows; later o rows
  __shared__ __align__(16) unsigned short Kb[NHT*SCB];   // k rows
  __shared__ __align__(16) unsigned short Vt[MD*NHT];    // V^T [d=128][ki=16]
  __shared__ __align__(16) unsigned short Pb[NHT*SCB];   // att rows (per-head 32-col slots)
  __shared__ __align__(16) unsigned short Tb[NHT*SCB];   // t bounce; later y bounce
  __shared__ __align__(16) unsigned short Ub[NHT*SCUF];  // FFN u, full width
  __shared__ __align__(16) float Bsm[NHEAD*NHT*NHT];

  const int tid = threadIdx.x;   // one wave per block/window
  const int wi  = blockIdx.x;
  const int lm  = tid & 15;
  const int lg  = tid >> 4;
  const f32x4 zero4 = {0.f,0.f,0.f,0.f};
  const bf8  zero8 = {0,0,0,0,0,0,0,0};

  // ========== Stage A: t = x @ W_in (hi-only) ==========
  bf8 xA[2];
  {
    const float* xp = x + (size_t)wi*1024 + lm*ED + lg*8;
#pragma unroll
    for (int kt = 0; kt < 2; ++kt){
      U8 h;
#pragma unroll
      for (int j = 0; j < 8; ++j) h.s[j] = bf1(xp[kt*32 + j]);
      xA[kt] = h.v;
    }
  }
  float tC[8][4];
#pragma unroll
  for (int nt = 0; nt < 8; ++nt){
    f32x4 acc = zero4;
#pragma unroll
    for (int kt = 0; kt < 2; ++kt){
      U8 w;
      if (useWin){
        w.q = pWin[(nt*2+kt)*64 + tid];
      } else {
        const float* wp = W_in + (size_t)(kt*32 + lg*8)*MD + nt*16 + lm;
#pragma unroll
        for (int j = 0; j < 8; ++j) w.s[j] = bf1(wp[(size_t)j*MD]);
      }
      acc = MFMA(xA[kt], w.v, acc, 0,0,0);
    }
#pragma unroll
    for (int r = 0; r < 4; ++r) tC[nt][r] = acc[r];
  }
  lnC(tC, g_in, b_in, lm);

  // ========== bounce t (bf16) -> A-frags ==========
#pragma unroll
  for (int nt = 0; nt < 8; ++nt)
#pragma unroll
    for (int r = 0; r < 4; ++r)
      Tb[(lg*4+r)*SCB + nt*16+lm] = bf1(tC[nt][r]);
  __syncthreads();
  bf8 tA[4];
#pragma unroll
  for (int kt = 0; kt < 4; ++kt)
    tA[kt] = *(const bf8*)(Tb + lm*SCB + kt*32 + lg*8);
  __syncthreads();

  // ========== Q,K (bf16 rows), V (transposed bf16) = t@W + b — pairwise prefetch ==========
#pragma unroll
  for (int nt = 0; nt < 8; nt += 2){
    U8 w0[4], w1[4];
#pragma unroll
    for (int kt = 0; kt < 4; ++kt) w0[kt].q = pWq[((nt+0)*4+kt)*64 + tid];
#pragma unroll
    for (int kt = 0; kt < 4; ++kt) w1[kt].q = pWq[((nt+1)*4+kt)*64 + tid];
    float b0 = bq[(nt+0)*16+lm], b1v = bq[(nt+1)*16+lm];
    f32x4 a0 = {b0,b0,b0,b0}, a1 = {b1v,b1v,b1v,b1v};
#pragma unroll
    for (int kt = 0; kt < 4; ++kt) a0 = MFMA(tA[kt], w0[kt].v, a0, 0,0,0);
#pragma unroll
    for (int kt = 0; kt < 4; ++kt) a1 = MFMA(tA[kt], w1[kt].v, a1, 0,0,0);
#pragma unroll
    for (int r = 0; r < 4; ++r){
      Qb[(lg*4+r)*SCB + (nt+0)*16+lm] = bf1(a0[r]);
      Qb[(lg*4+r)*SCB + (nt+1)*16+lm] = bf1(a1[r]);
    }
  }
#pragma unroll
  for (int nt = 0; nt < 8; nt += 2){
    U8 w0[4], w1[4];
#pragma unroll
    for (int kt = 0; kt < 4; ++kt) w0[kt].q = pWk[((nt+0)*4+kt)*64 + tid];
#pragma unroll
    for (int kt = 0; kt < 4; ++kt) w1[kt].q = pWk[((nt+1)*4+kt)*64 + tid];
    float b0 = bk[(nt+0)*16+lm], b1v = bk[(nt+1)*16+lm];
    f32x4 a0 = {b0,b0,b0,b0}, a1 = {b1v,b1v,b1v,b1v};
#pragma unroll
    for (int kt = 0; kt < 4; ++kt) a0 = MFMA(tA[kt], w0[kt].v, a0, 0,0,0);
#pragma unroll
    for (int kt = 0; kt < 4; ++kt) a1 = MFMA(tA[kt], w1[kt].v, a1, 0,0,0);
#pragma unroll
    for (int r = 0; r < 4; ++r){
      Kb[(lg*4+r)*SCB + (nt+0)*16+lm] = bf1(a0[r]);
      Kb[(lg*4+r)*SCB + (nt+1)*16+lm] = bf1(a1[r]);
    }
  }
#pragma unroll
  for (int nt = 0; nt < 8; nt += 2){
    U8 w0[4], w1[4];
#pragma unroll
    for (int kt = 0; kt < 4; ++kt) w0[kt].q = pWv[((nt+0)*4+kt)*64 + tid];
#pragma unroll
    for (int kt = 0; kt < 4; ++kt) w1[kt].q = pWv[((nt+1)*4+kt)*64 + tid];
    float b0 = bv[(nt+0)*16+lm], b1v = bv[(nt+1)*16+lm];
    f32x4 a0 = {b0,b0,b0,b0}, a1 = {b1v,b1v,b1v,b1v};
#pragma unroll
    for (int kt = 0; kt < 4; ++kt) a0 = MFMA(tA[kt], w0[kt].v, a0, 0,0,0);
#pragma unroll
    for (int kt = 0; kt < 4; ++kt) a1 = MFMA(tA[kt], w1[kt].v, a1, 0,0,0);
    // V^T store: Vt[d][ki], d = col = nt*16+lm, ki = row = lg*4+r
#pragma unroll
    for (int r = 0; r < 4; ++r){
      Vt[((nt+0)*16+lm)*NHT + lg*4+r] = bf1(a0[r]);
      Vt[((nt+1)*16+lm)*NHT + lg*4+r] = bf1(a1[r]);
    }
  }

  // ========== rel-pos bias: load precomputed values (biask) into Bsm ==========
  {
    const float* bp = out + (size_t)wi*2048;
    for (int p = tid; p < NHT*NHT; p += 64){
      Bsm[0*256 + p] = bp[0*256 + p];
      Bsm[1*256 + p] = bp[1*256 + p];
      Bsm[2*256 + p] = bp[2*256 + p];
      Bsm[3*256 + p] = bp[3*256 + p];
    }
  }
  __syncthreads();

  // ========== attention via MFMA (r13/r17-verified construction) ==========
  bf8 qA[4], kB[4];
#pragma unroll
  for (int h = 0; h < 4; ++h){
    qA[h] = *(const bf8*)(Qb + lm*SCB + h*32 + lg*8);
    kB[h] = *(const bf8*)(Kb + lm*SCB + h*32 + lg*8);
  }
#pragma unroll
  for (int h = 0; h < 4; ++h){
    f32x4 s = MFMA(qA[h], kB[h], zero4, 0,0,0);
#pragma unroll
    for (int r = 0; r < 4; ++r){
      float v = fmaf(s[r], SCALE, Bsm[h*256 + (lg*4+r)*16 + lm]);
      float mx = v;
#pragma unroll
      for (int m = 1; m < 16; m <<= 1) mx = fmaxf(mx, __shfl_xor(mx, m));
      float e = __expf(v - mx);
      float sm = e;
#pragma unroll
      for (int m = 1; m < 16; m <<= 1) sm += __shfl_xor(sm, m);
      Pb[(lg*4+r)*SCB + h*32 + lm] = bf1(e * __builtin_amdgcn_rcpf(sm));
    }
  }
  __syncthreads();

  // PV: O_h = P_h @ V_h  (K=32, upper 16 k zeroed via A)
#pragma unroll
  for (int h = 0; h < 4; ++h){
    bf8 aP = *(const bf8*)(Pb + lm*SCB + h*32 + lg*8);
    if (tid >= 32) aP = zero8;        // k = lg*8+j >= 16 -> zero contribution
#pragma unroll
    for (int n2 = 0; n2 < 2; ++n2){
      bf8 vB = *(const bf8*)(Vt + (h*32 + n2*16 + lm)*NHT + (lg & 1)*8);
      if (tid >= 32) vB = zero8;
      f32x4 o = MFMA(aP, vB, zero4, 0,0,0);
#pragma unroll
      for (int r = 0; r < 4; ++r)
        Qb[(lg*4+r)*SCB + h*32 + n2*16 + lm] = bf1(o[r]);
    }
  }
  __syncthreads();

  // ========== att_out = o@Wo + bo, residual, LN1 — pairwise prefetch ==========
  bf8 oA[4];
#pragma unroll
  for (int kt = 0; kt < 4; ++kt)
    oA[kt] = *(const bf8*)(Qb + lm*SCB + kt*32 + lg*8);
#pragma unroll
  for (int nt = 0; nt < 8; nt += 2){
    U8 w0[4], w1[4];
#pragma unroll
    for (int kt = 0; kt < 4; ++kt) w0[kt].q = pWo[((nt+0)*4+kt)*64 + tid];
#pragma unroll
    for (int kt = 0; kt < 4; ++kt) w1[kt].q = pWo[((nt+1)*4+kt)*64 + tid];
    float b0 = bo[(nt+0)*16+lm], b1v = bo[(nt+1)*16+lm];
    f32x4 a0 = {b0,b0,b0,b0}, a1 = {b1v,b1v,b1v,b1v};
#pragma unroll
    for (int kt = 0; kt < 4; ++kt) a0 = MFMA(oA[kt], w0[kt].v, a0, 0,0,0);
#pragma unroll
    for (int kt = 0; kt < 4; ++kt) a1 = MFMA(oA[kt], w1[kt].v, a1, 0,0,0);
#pragma unroll
    for (int r = 0; r < 4; ++r){
      tC[nt+0][r] += a0[r];
      tC[nt+1][r] += a1[r];
    }
  }
  lnC(tC, g1, b1, lm);
  __syncthreads();

  // ========== bounce y (bf16) -> A-frags ==========
#pragma unroll
  for (int nt = 0; nt < 8; ++nt)
#pragma unroll
    for (int r = 0; r < 4; ++r)
      Tb[(lg*4+r)*SCB + nt*16+lm] = bf1(tC[nt][r]);
  __syncthreads();
  bf8 yA[4];
#pragma unroll
  for (int kt = 0; kt < 4; ++kt)
    yA[kt] = *(const bf8*)(Tb + lm*SCB + kt*32 + lg*8);
  __syncthreads();

  // ========== FFN1 all 16 tiles (pairwise prefetch) -> Ub, ONE barrier, FFN2 ==========
#pragma unroll
  for (int nt1 = 0; nt1 < 16; nt1 += 2){
    U8 w0[4], w1[4];
#pragma unroll
    for (int kt = 0; kt < 4; ++kt) w0[kt].q = pW1[((nt1+0)*4+kt)*64 + tid];
#pragma unroll
    for (int kt = 0; kt < 4; ++kt) w1[kt].q = pW1[((nt1+1)*4+kt)*64 + tid];
    f32x4 a0 = zero4, a1 = zero4;
#pragma unroll
    for (int kt = 0; kt < 4; ++kt) a0 = MFMA(yA[kt], w0[kt].v, a0, 0,0,0);
#pragma unroll
    for (int kt = 0; kt < 4; ++kt) a1 = MFMA(yA[kt], w1[kt].v, a1, 0,0,0);
#pragma unroll
    for (int r = 0; r < 4; ++r){
      Ub[(lg*4+r)*SCUF + (nt1+0)*16 + lm] = bf1(silu_f(a0[r]));
      Ub[(lg*4+r)*SCUF + (nt1+1)*16 + lm] = bf1(silu_f(a1[r]));
    }
  }
  __syncthreads();
  f32x4 acc2[8];
#pragma unroll
  for (int nt = 0; nt < 8; ++nt) acc2[nt] = zero4;
#pragma unroll
  for (int kt2 = 0; kt2 < 8; ++kt2){
    bf8 uA = *(const bf8*)(Ub + lm*SCUF + kt2*32 + lg*8);
    U8 wv2[8];
#pragma unroll
    for (int nt = 0; nt < 8; ++nt) wv2[nt].q = pW2[(nt*8+kt2)*64 + tid];
#pragma unroll
    for (int nt = 0; nt < 8; ++nt)
      acc2[nt] = MFMA(uA, wv2[nt].v, acc2[nt], 0,0,0);
  }

  // ========== residual2, LN2, store ==========
#pragma unroll
  for (int nt = 0; nt < 8; ++nt)
#pragma unroll
    for (int r = 0; r < 4; ++r) tC[nt][r] += acc2[nt][r];
  lnC(tC, g2, b2, lm);

  float* op = out + (size_t)wi*(NHT*MD);
#pragma unroll
  for (int nt = 0; nt < 8; ++nt)
#pragma unroll
    for (int r = 0; r < 4; ++r)
      op[(lg*4+r)*MD + nt*16+lm] = tC[nt][r];
}

extern "C" void kernel_launch(void* const* d_in, const int* in_sizes, int n_in,
                              void* d_out, int out_size, void* d_ws, size_t ws_size,
                              hipStream_t stream) {
  const float* x     = (const float*)d_in[0];
  const float* pos1  = (const float*)d_in[1];
  const float* pos2  = (const float*)d_in[2];
  const float* W_in  = (const float*)d_in[3];
  const float* g_in  = (const float*)d_in[4];
  const float* b_in  = (const float*)d_in[5];
  const float* W_pe  = (const float*)d_in[6];
  const float* W_bias= (const float*)d_in[7];
  const float* Wq    = (const float*)d_in[8];
  const float* bq    = (const float*)d_in[9];
  const float* Wk    = (const float*)d_in[10];
  const float* bk    = (const float*)d_in[11];
  const float* Wv    = (const float*)d_in[12];
  const float* bv    = (const float*)d_in[13];
  const float* Wo    = (const float*)d_in[14];
  const float* bo    = (const float*)d_in[15];
  const float* W1    = (const float*)d_in[16];
  const float* W2    = (const float*)d_in[17];
  const float* g1    = (const float*)d_in[18];
  const float* b1    = (const float*)d_in[19];
  const float* g2    = (const float*)d_in[20];
  const float* b2    = (const float*)d_in[21];
  float* out = (float*)d_out;
  uint4* ws  = (uint4*)d_ws;   // 16384 units (256 KiB) + optional 1024 for W_in

  const int useWin = (ws_size >= (size_t)(16384 + 1024) * 16) ? 1 : 0;

  const int nwin = in_sizes[0] / (NHT * ED);   // 16384

  packw<<<64, 256, 0, stream>>>(Wq, Wk, Wv, Wo, W1, W2, ws);
  if (useWin) packwin<<<4, 256, 0, stream>>>(W_in, ws);
  biask<<<nwin, 64, 0, stream>>>(pos1, pos2, W_pe, W_bias, out);

  nha_mfma<<<nwin, 64, 0, stream>>>(x, W_in, g_in, b_in,
                                    bq, bk, bv, bo, g1, b1, g2, b2, ws, useWin, out);
}